// Round 2
// baseline (718.582 us; speedup 1.0000x reference)
//
#include <hip/hip_runtime.h>
#include <hip/hip_bf16.h>

#define NB    10
#define HW    36864      // 192*192
#define CIN   128
#define COUT  64
#define BATCH 16

typedef float f32x4 __attribute__((ext_vector_type(4)));

// ws float layout:
//  [0] dmin, [1] width
//  [2..12)    counts[10]
//  [16..1296) S[10][128]   (bin-major)
//  [1296..1936) means[10][64]
//  [2048..2112) pmin[64], [2112..2176) pmax[64]

__device__ __forceinline__ float wred_sum(float v){
  #pragma unroll
  for (int off = 32; off; off >>= 1) v += __shfl_xor(v, off, 64);
  return v;
}

__device__ __forceinline__ int bin_of(float d, float dmin, float width){
  float t = (d - dmin) / width;   // IEEE f32 div, matches reference exactly
  int bn = (int)floorf(t);
  return min(max(bn, 0), NB - 1);
}

__device__ __forceinline__ float sel10(const float* m, int bn){
  float v = m[0];
  #pragma unroll
  for (int j = 1; j < NB; j++) v = (bn == j) ? m[j] : v;
  return v;
}

// ---- K1: per-block partial min/max of depth (64 blocks x 256 threads x 9 float4)
__global__ __launch_bounds__(256) void k_minmax(const float* __restrict__ depth,
                                                float* __restrict__ ws){
  const int tid = threadIdx.x;
  const int g = blockIdx.x * 256 + tid;
  const float4* dq = (const float4*)depth;
  float mn = 1e30f, mx = -1e30f;
  #pragma unroll
  for (int i = 0; i < 9; i++){
    float4 v = dq[g + i * 16384];   // 64*256 = 16384 threads; 16384*9*4 = 589824
    mn = fminf(mn, fminf(fminf(v.x, v.y), fminf(v.z, v.w)));
    mx = fmaxf(mx, fmaxf(fmaxf(v.x, v.y), fmaxf(v.z, v.w)));
  }
  #pragma unroll
  for (int off = 32; off; off >>= 1){
    mn = fminf(mn, __shfl_xor(mn, off, 64));
    mx = fmaxf(mx, __shfl_xor(mx, off, 64));
  }
  __shared__ float smn[4], smx[4];
  const int lane = tid & 63, wv = tid >> 6;
  if (lane == 0){ smn[wv] = mn; smx[wv] = mx; }
  __syncthreads();
  if (tid == 0){
    float a = smn[0], b = smx[0];
    #pragma unroll
    for (int w = 1; w < 4; w++){ a = fminf(a, smn[w]); b = fmaxf(b, smx[w]); }
    ws[2048 + blockIdx.x] = a;
    ws[2112 + blockIdx.x] = b;
  }
}

// ---- K2: finalize min/max -> dmin,width; zero counts + S (ws is poisoned each call)
__global__ __launch_bounds__(256) void k_finalize(float* __restrict__ ws){
  const int tid = threadIdx.x;
  if (tid < 64){
    float mn = ws[2048 + tid], mx = ws[2112 + tid];
    #pragma unroll
    for (int off = 32; off; off >>= 1){
      mn = fminf(mn, __shfl_xor(mn, off, 64));
      mx = fmaxf(mx, __shfl_xor(mx, off, 64));
    }
    if (tid == 0){ ws[0] = mn; ws[1] = (mx - mn) / (float)NB; }
  }
  for (int i = 2 + tid; i < 1296; i += 256) ws[i] = 0.0f;
}

// ---- K4: per-bin per-channel feature sums (+counts from cg==0 blocks)
// grid = 16 b * 32 cgroups * 4 pixel-chunks = 2048 blocks
__global__ __launch_bounds__(256, 4) void k_binsum(const float* __restrict__ feat,
                                                   const float* __restrict__ depth,
                                                   float* __restrict__ ws){
  const int tid = threadIdx.x;
  const int pc  = blockIdx.x & 3;
  const int cg  = (blockIdx.x >> 2) & 31;
  const int b   = blockIdx.x >> 7;
  const float dmin = ws[0], width = ws[1];
  const int c0 = cg * 4;
  const float4* __restrict__ dq  = (const float4*)(depth + (size_t)b * HW);
  const float4* __restrict__ fp0 = (const float4*)(feat + (size_t)(b * CIN + c0 + 0) * HW);
  const float4* __restrict__ fp1 = (const float4*)(feat + (size_t)(b * CIN + c0 + 1) * HW);
  const float4* __restrict__ fp2 = (const float4*)(feat + (size_t)(b * CIN + c0 + 2) * HW);
  const float4* __restrict__ fp3 = (const float4*)(feat + (size_t)(b * CIN + c0 + 3) * HW);

  float acc0[NB], acc1[NB], acc2[NB], acc3[NB], cnt[NB];
  #pragma unroll
  for (int j = 0; j < NB; j++){ acc0[j]=0.f; acc1[j]=0.f; acc2[j]=0.f; acc3[j]=0.f; cnt[j]=0.f; }

  const int qbase = pc * 2304 + tid;   // 9216/4 chunks of 2304 quads
  #pragma unroll 3
  for (int it = 0; it < 9; it++){
    const int q = qbase + it * 256;
    const float4 dv = dq[q];
    const float4 v0 = fp0[q], v1 = fp1[q], v2 = fp2[q], v3 = fp3[q];
    const float de[4] = {dv.x, dv.y, dv.z, dv.w};
    const float e0[4] = {v0.x, v0.y, v0.z, v0.w};
    const float e1[4] = {v1.x, v1.y, v1.z, v1.w};
    const float e2[4] = {v2.x, v2.y, v2.z, v2.w};
    const float e3[4] = {v3.x, v3.y, v3.z, v3.w};
    #pragma unroll
    for (int e = 0; e < 4; e++){
      const int bn = bin_of(de[e], dmin, width);
      float w[NB];
      #pragma unroll
      for (int j = 0; j < NB; j++) w[j] = (bn == j) ? 1.0f : 0.0f;
      #pragma unroll
      for (int j = 0; j < NB; j++){
        acc0[j] = fmaf(e0[e], w[j], acc0[j]);
        acc1[j] = fmaf(e1[e], w[j], acc1[j]);
        acc2[j] = fmaf(e2[e], w[j], acc2[j]);
        acc3[j] = fmaf(e3[e], w[j], acc3[j]);
      }
      if (cg == 0){
        #pragma unroll
        for (int j = 0; j < NB; j++) cnt[j] += w[j];
      }
    }
  }

  __shared__ float red[4][40];
  __shared__ float redc[4][NB];
  const int lane = tid & 63, wv = tid >> 6;
  #pragma unroll
  for (int j = 0; j < NB; j++){
    float r0 = wred_sum(acc0[j]);
    float r1 = wred_sum(acc1[j]);
    float r2 = wred_sum(acc2[j]);
    float r3 = wred_sum(acc3[j]);
    if (lane == 0){
      red[wv][ 0 + j] = r0; red[wv][10 + j] = r1;
      red[wv][20 + j] = r2; red[wv][30 + j] = r3;
    }
    if (cg == 0){
      float rc = wred_sum(cnt[j]);
      if (lane == 0) redc[wv][j] = rc;
    }
  }
  __syncthreads();
  if (tid < 40){
    const int ch = tid / NB, j = tid - ch * NB;
    const float s = red[0][tid] + red[1][tid] + red[2][tid] + red[3][tid];
    unsafeAtomicAdd(&ws[16 + j * CIN + c0 + ch], s);
  }
  if (cg == 0 && tid < NB){
    const float s = redc[0][tid] + redc[1][tid] + redc[2][tid] + redc[3][tid];
    unsafeAtomicAdd(&ws[2 + tid], s);
  }
}

// ---- K5: means[bin][o] = (W[o,:] . S[bin,:] + cnt*bias[o]) / max(cnt,1)
__global__ void k_means(const float* __restrict__ wgt, const float* __restrict__ bias,
                        float* __restrict__ ws){
  const int tid = threadIdx.x;          // 640 threads: bin = tid>>6, o = tid&63
  const int o = tid & 63, bin = tid >> 6;
  const float cnt = ws[2 + bin];
  const float* Wr = wgt + o * CIN;
  const float* Sr = ws + 16 + bin * CIN;
  float s = 0.0f;
  #pragma unroll 8
  for (int c = 0; c < CIN; c++) s = fmaf(Wr[c], Sr[c], s);
  s += cnt * bias[o];
  ws[1296 + bin * 64 + o] = s / fmaxf(cnt, 1.0f);
}

// ---- K6: out[b,o,h,w] = means[bin(b,h,w)][o]
// grid = 16 b * 16 ogroups * 4 pixel-chunks = 1024 blocks
__global__ __launch_bounds__(256, 4) void k_scatter(const float* __restrict__ depth,
                                                    const float* __restrict__ ws,
                                                    float* __restrict__ out){
  const int tid = threadIdx.x;
  const int pc  = blockIdx.x & 3;
  const int og  = (blockIdx.x >> 2) & 15;
  const int b   = blockIdx.x >> 6;
  const float dmin = ws[0], width = ws[1];
  float m0[NB], m1[NB], m2[NB], m3[NB];
  #pragma unroll
  for (int j = 0; j < NB; j++){
    m0[j] = ws[1296 + j * 64 + og * 4 + 0];
    m1[j] = ws[1296 + j * 64 + og * 4 + 1];
    m2[j] = ws[1296 + j * 64 + og * 4 + 2];
    m3[j] = ws[1296 + j * 64 + og * 4 + 3];
  }
  const float4* __restrict__ dq = (const float4*)(depth + (size_t)b * HW);
  float* __restrict__ o0 = out + (size_t)(b * COUT + og * 4 + 0) * HW;
  float* __restrict__ o1 = out + (size_t)(b * COUT + og * 4 + 1) * HW;
  float* __restrict__ o2 = out + (size_t)(b * COUT + og * 4 + 2) * HW;
  float* __restrict__ o3 = out + (size_t)(b * COUT + og * 4 + 3) * HW;

  const int qbase = pc * 2304 + tid;
  #pragma unroll 3
  for (int it = 0; it < 9; it++){
    const int q = qbase + it * 256;
    const float4 dv = dq[q];
    const float de[4] = {dv.x, dv.y, dv.z, dv.w};
    int bn[4];
    #pragma unroll
    for (int e = 0; e < 4; e++) bn[e] = bin_of(de[e], dmin, width);
    f32x4 r0, r1, r2, r3;
    #pragma unroll
    for (int e = 0; e < 4; e++){
      r0[e] = sel10(m0, bn[e]);
      r1[e] = sel10(m1, bn[e]);
      r2[e] = sel10(m2, bn[e]);
      r3[e] = sel10(m3, bn[e]);
    }
    __builtin_nontemporal_store(r0, (f32x4*)(o0 + 4 * (size_t)q));
    __builtin_nontemporal_store(r1, (f32x4*)(o1 + 4 * (size_t)q));
    __builtin_nontemporal_store(r2, (f32x4*)(o2 + 4 * (size_t)q));
    __builtin_nontemporal_store(r3, (f32x4*)(o3 + 4 * (size_t)q));
  }
}

extern "C" void kernel_launch(void* const* d_in, const int* in_sizes, int n_in,
                              void* d_out, int out_size, void* d_ws, size_t ws_size,
                              hipStream_t stream){
  const float* feat  = (const float*)d_in[0];
  const float* depth = (const float*)d_in[1];
  const float* wgt   = (const float*)d_in[2];
  const float* bias  = (const float*)d_in[3];
  float* out = (float*)d_out;
  float* ws  = (float*)d_ws;

  k_minmax  <<<dim3(64),   dim3(256), 0, stream>>>(depth, ws);
  k_finalize<<<dim3(1),    dim3(256), 0, stream>>>(ws);
  k_binsum  <<<dim3(2048), dim3(256), 0, stream>>>(feat, depth, ws);
  k_means   <<<dim3(1),    dim3(640), 0, stream>>>(wgt, bias, ws);
  k_scatter <<<dim3(1024), dim3(256), 0, stream>>>(depth, ws, out);
}

// Round 3
// 499.884 us; speedup vs baseline: 1.4375x; 1.4375x over previous
//
#include <hip/hip_runtime.h>
#include <hip/hip_bf16.h>

#define NB    10
#define HW    36864      // 192*192
#define QP    9216       // HW/4 quads per plane
#define CIN   128
#define COUT  64
#define BATCH 16

typedef float f32x4 __attribute__((ext_vector_type(4)));

// ws layout (float32 indices unless noted):
//  [16..1296)    S[10][128]      (bin-major channel sums)
//  [1296..1936)  means[10][64]
//  [2048..2112)  partial min[64]
//  [2112..2176)  partial max[64]
//  [2560..3584)  count partials [64 blocks][16 stride, bins 0..9]
//  byte offset 16384 .. 16384+589824: bin_id u8 map [16][36864]

__device__ __forceinline__ float wred_sum(float v){
  #pragma unroll
  for (int off = 32; off; off >>= 1) v += __shfl_xor(v, off, 64);
  return v;
}

__device__ __forceinline__ int bin_of(float d, float dmin, float width){
  float t = (d - dmin) / width;   // IEEE f32 div — must match reference bit-exactly
  int bn = (int)floorf(t);
  return min(max(bn, 0), NB - 1);
}

__device__ __forceinline__ float sel10(const float* m, int bn){
  float v = m[0];
  #pragma unroll
  for (int j = 1; j < NB; j++) v = (bn == j) ? m[j] : v;
  return v;
}

// ---- K1: per-block partial min/max of depth (64 blocks x 256 threads x 9 float4)
__global__ __launch_bounds__(256) void k_minmax(const float* __restrict__ depth,
                                                float* __restrict__ ws){
  const int tid = threadIdx.x;
  const int g = blockIdx.x * 256 + tid;
  const float4* dq = (const float4*)depth;
  float mn = 1e30f, mx = -1e30f;
  #pragma unroll
  for (int i = 0; i < 9; i++){
    float4 v = dq[g + i * 16384];
    mn = fminf(mn, fminf(fminf(v.x, v.y), fminf(v.z, v.w)));
    mx = fmaxf(mx, fmaxf(fmaxf(v.x, v.y), fmaxf(v.z, v.w)));
  }
  #pragma unroll
  for (int off = 32; off; off >>= 1){
    mn = fminf(mn, __shfl_xor(mn, off, 64));
    mx = fmaxf(mx, __shfl_xor(mx, off, 64));
  }
  __shared__ float smn[4], smx[4];
  const int lane = tid & 63, wv = tid >> 6;
  if (lane == 0){ smn[wv] = mn; smx[wv] = mx; }
  __syncthreads();
  if (tid == 0){
    float a = smn[0], b = smx[0];
    #pragma unroll
    for (int w = 1; w < 4; w++){ a = fminf(a, smn[w]); b = fmaxf(b, smx[w]); }
    ws[2048 + blockIdx.x] = a;
    ws[2112 + blockIdx.x] = b;
  }
}

// ---- K2: bin-id map (u8) + per-block count partials; block 0 zeros S.
// 64 blocks x 256 threads x 9 quads.
__global__ __launch_bounds__(256) void k_binmap(const float* __restrict__ depth,
                                                float* __restrict__ ws){
  const int tid = threadIdx.x;
  __shared__ float sdm, swd;
  if (tid < 64){
    float mn = ws[2048 + tid], mx = ws[2112 + tid];
    #pragma unroll
    for (int off = 32; off; off >>= 1){
      mn = fminf(mn, __shfl_xor(mn, off, 64));
      mx = fmaxf(mx, __shfl_xor(mx, off, 64));
    }
    if (tid == 0){ sdm = mn; swd = (mx - mn) / (float)NB; }
  }
  if (blockIdx.x == 0){
    for (int i = 16 + tid; i < 1296; i += 256) ws[i] = 0.0f;   // zero S
  }
  __syncthreads();
  const float dmin = sdm, width = swd;
  uchar4* __restrict__ bm = (uchar4*)((char*)ws + 16384);
  const float4* __restrict__ dq = (const float4*)depth;
  const int g = blockIdx.x * 256 + tid;
  float cnt[NB];
  #pragma unroll
  for (int j = 0; j < NB; j++) cnt[j] = 0.0f;
  #pragma unroll
  for (int i = 0; i < 9; i++){
    const float4 v = dq[g + i * 16384];
    const int b0 = bin_of(v.x, dmin, width);
    const int b1 = bin_of(v.y, dmin, width);
    const int b2 = bin_of(v.z, dmin, width);
    const int b3 = bin_of(v.w, dmin, width);
    uchar4 r;
    r.x = (unsigned char)b0; r.y = (unsigned char)b1;
    r.z = (unsigned char)b2; r.w = (unsigned char)b3;
    bm[g + i * 16384] = r;
    #pragma unroll
    for (int j = 0; j < NB; j++){
      cnt[j] += (b0 == j) ? 1.0f : 0.0f;
      cnt[j] += (b1 == j) ? 1.0f : 0.0f;
      cnt[j] += (b2 == j) ? 1.0f : 0.0f;
      cnt[j] += (b3 == j) ? 1.0f : 0.0f;
    }
  }
  __shared__ float redc[4][NB];
  const int lane = tid & 63, wv = tid >> 6;
  #pragma unroll
  for (int j = 0; j < NB; j++){
    float rc = wred_sum(cnt[j]);
    if (lane == 0) redc[wv][j] = rc;
  }
  __syncthreads();
  if (tid < NB){
    ws[2560 + blockIdx.x * 16 + tid] =
        redc[0][tid] + redc[1][tid] + redc[2][tid] + redc[3][tid];
  }
}

// ---- K3: per-bin per-channel feature sums
// grid = 16 b * 32 cgroups * 4 pixel-chunks = 2048 blocks
__global__ __launch_bounds__(256, 4) void k_binsum(const float* __restrict__ feat,
                                                   float* __restrict__ ws){
  const int tid = threadIdx.x;
  const int pc  = blockIdx.x & 3;
  const int cg  = (blockIdx.x >> 2) & 31;
  const int b   = blockIdx.x >> 7;
  const int c0 = cg * 4;
  const uchar4* __restrict__ bm = (const uchar4*)((const char*)ws + 16384) + (size_t)b * QP;
  const f32x4* __restrict__ fp0 = (const f32x4*)(feat + (size_t)(b * CIN + c0 + 0) * HW);
  const f32x4* __restrict__ fp1 = (const f32x4*)(feat + (size_t)(b * CIN + c0 + 1) * HW);
  const f32x4* __restrict__ fp2 = (const f32x4*)(feat + (size_t)(b * CIN + c0 + 2) * HW);
  const f32x4* __restrict__ fp3 = (const f32x4*)(feat + (size_t)(b * CIN + c0 + 3) * HW);

  float acc0[NB], acc1[NB], acc2[NB], acc3[NB];
  #pragma unroll
  for (int j = 0; j < NB; j++){ acc0[j]=0.f; acc1[j]=0.f; acc2[j]=0.f; acc3[j]=0.f; }

  const int qbase = pc * 2304 + tid;
  #pragma unroll 3
  for (int it = 0; it < 9; it++){
    const int q = qbase + it * 256;
    const uchar4 bq = bm[q];
    const f32x4 v0 = __builtin_nontemporal_load(fp0 + q);
    const f32x4 v1 = __builtin_nontemporal_load(fp1 + q);
    const f32x4 v2 = __builtin_nontemporal_load(fp2 + q);
    const f32x4 v3 = __builtin_nontemporal_load(fp3 + q);
    const int bn[4] = {bq.x, bq.y, bq.z, bq.w};
    #pragma unroll
    for (int e = 0; e < 4; e++){
      float w[NB];
      #pragma unroll
      for (int j = 0; j < NB; j++) w[j] = (bn[e] == j) ? 1.0f : 0.0f;
      #pragma unroll
      for (int j = 0; j < NB; j++){
        acc0[j] = fmaf(v0[e], w[j], acc0[j]);
        acc1[j] = fmaf(v1[e], w[j], acc1[j]);
        acc2[j] = fmaf(v2[e], w[j], acc2[j]);
        acc3[j] = fmaf(v3[e], w[j], acc3[j]);
      }
    }
  }

  __shared__ float red[4][40];
  const int lane = tid & 63, wv = tid >> 6;
  #pragma unroll
  for (int j = 0; j < NB; j++){
    float r0 = wred_sum(acc0[j]);
    float r1 = wred_sum(acc1[j]);
    float r2 = wred_sum(acc2[j]);
    float r3 = wred_sum(acc3[j]);
    if (lane == 0){
      red[wv][ 0 + j] = r0; red[wv][10 + j] = r1;
      red[wv][20 + j] = r2; red[wv][30 + j] = r3;
    }
  }
  __syncthreads();
  if (tid < 40){
    const int ch = tid / NB, j = tid - ch * NB;
    const float s = red[0][tid] + red[1][tid] + red[2][tid] + red[3][tid];
    unsafeAtomicAdd(&ws[16 + j * CIN + c0 + ch], s);
  }
}

// ---- K4: counts finalize + means[bin][o] = (W[o,:].S[bin,:] + cnt*bias[o]) / max(cnt,1)
__global__ void k_means(const float* __restrict__ wgt, const float* __restrict__ bias,
                        float* __restrict__ ws){
  const int tid = threadIdx.x;          // 640 threads: bin = tid>>6, o = tid&63
  const int o = tid & 63, bin = tid >> 6;
  float cnt = 0.0f;
  #pragma unroll 8
  for (int k = 0; k < 64; k++) cnt += ws[2560 + k * 16 + bin];
  const float* Wr = wgt + o * CIN;
  const float* Sr = ws + 16 + bin * CIN;
  float s = 0.0f;
  #pragma unroll 8
  for (int c = 0; c < CIN; c++) s = fmaf(Wr[c], Sr[c], s);
  s += cnt * bias[o];
  ws[1296 + bin * 64 + o] = s / fmaxf(cnt, 1.0f);
}

// ---- K5: out[b,o,h,w] = means[bin(b,h,w)][o]
// grid = 16 b * 16 ogroups * 4 pixel-chunks = 1024 blocks
__global__ __launch_bounds__(256, 4) void k_scatter(const float* __restrict__ ws,
                                                    float* __restrict__ out){
  const int tid = threadIdx.x;
  const int pc  = blockIdx.x & 3;
  const int og  = (blockIdx.x >> 2) & 15;
  const int b   = blockIdx.x >> 6;
  float m0[NB], m1[NB], m2[NB], m3[NB];
  #pragma unroll
  for (int j = 0; j < NB; j++){
    m0[j] = ws[1296 + j * 64 + og * 4 + 0];
    m1[j] = ws[1296 + j * 64 + og * 4 + 1];
    m2[j] = ws[1296 + j * 64 + og * 4 + 2];
    m3[j] = ws[1296 + j * 64 + og * 4 + 3];
  }
  const uchar4* __restrict__ bm = (const uchar4*)((const char*)ws + 16384) + (size_t)b * QP;
  float* __restrict__ o0 = out + (size_t)(b * COUT + og * 4 + 0) * HW;
  float* __restrict__ o1 = out + (size_t)(b * COUT + og * 4 + 1) * HW;
  float* __restrict__ o2 = out + (size_t)(b * COUT + og * 4 + 2) * HW;
  float* __restrict__ o3 = out + (size_t)(b * COUT + og * 4 + 3) * HW;

  const int qbase = pc * 2304 + tid;
  #pragma unroll 3
  for (int it = 0; it < 9; it++){
    const int q = qbase + it * 256;
    const uchar4 bq = bm[q];
    const int bn[4] = {bq.x, bq.y, bq.z, bq.w};
    f32x4 r0, r1, r2, r3;
    #pragma unroll
    for (int e = 0; e < 4; e++){
      r0[e] = sel10(m0, bn[e]);
      r1[e] = sel10(m1, bn[e]);
      r2[e] = sel10(m2, bn[e]);
      r3[e] = sel10(m3, bn[e]);
    }
    __builtin_nontemporal_store(r0, (f32x4*)(o0 + 4 * (size_t)q));
    __builtin_nontemporal_store(r1, (f32x4*)(o1 + 4 * (size_t)q));
    __builtin_nontemporal_store(r2, (f32x4*)(o2 + 4 * (size_t)q));
    __builtin_nontemporal_store(r3, (f32x4*)(o3 + 4 * (size_t)q));
  }
}

extern "C" void kernel_launch(void* const* d_in, const int* in_sizes, int n_in,
                              void* d_out, int out_size, void* d_ws, size_t ws_size,
                              hipStream_t stream){
  const float* feat  = (const float*)d_in[0];
  const float* depth = (const float*)d_in[1];
  const float* wgt   = (const float*)d_in[2];
  const float* bias  = (const float*)d_in[3];
  float* out = (float*)d_out;
  float* ws  = (float*)d_ws;

  k_minmax <<<dim3(64),   dim3(256), 0, stream>>>(depth, ws);
  k_binmap <<<dim3(64),   dim3(256), 0, stream>>>(depth, ws);
  k_binsum <<<dim3(2048), dim3(256), 0, stream>>>(feat, ws);
  k_means  <<<dim3(1),    dim3(640), 0, stream>>>(wgt, bias, ws);
  k_scatter<<<dim3(1024), dim3(256), 0, stream>>>(ws, out);
}